// Round 2
// baseline (792.655 us; speedup 1.0000x reference)
//
#include <hip/hip_runtime.h>
#include <math.h>
#include <stdint.h>

// ConvLSTM (Seq2VecRNN2D) round 7: round-0 skeleton (tap-granularity, counted vmcnt)
// + W quad-buffer (stage lin+3) + register-double-buffered fragment reads
// (tap t issues tap t+1's 12 ds_reads during t's MFMA phase) + s_setprio around
// MFMA. LDS = 2x32KB A + 4x16KB W = 128 KiB. 3-term bf16-split MFMA, fused LSTM.
// B=8 T=8 CIN=128 HID=64 G=256 H=W=32.
//
// Activation image per (slot,b,cg32): [34 y'][34 px][8 blk of 16B], blk = pl*4+kg
// stored at blk^(px&7); ch = cg*32+kg*8+j, pl0=hi bf16, pl1=lo bf16. Borders zero.
// Weight image per (combo,cg,tap,nt): [pl][4 g][16 hcp][8 b8 of 16B], b8 = kg+4*(hc&1)
// stored at b8^(hcp&7); hcp = hc_local>>1.
//
// vmcnt schedule (in-order retirement, verified by queue simulation):
//   prologue: A0(4),W0(2),W1(2),W2(2); wait vmcnt(4) -> [W1,W2]
//   tap t: wait CNT then stage W[t+3] (+A at tap0). CNT = 6 for tap%9 in {1,2},
//   else 2. Every wait drains only stages issued >=2 taps earlier, and after the
//   wait W[t+1] is complete -> safe to early-read t+1's fragments during tap t.
//   Slot of W[t+1] is restaged as W[t+5] (issued at t+2, one barrier after all
//   waves lgkm-drained their reads of W[t+1]) -> no read/DMA race.

typedef __attribute__((ext_vector_type(8))) short short8;
typedef __attribute__((ext_vector_type(4))) float float4v;

namespace {
constexpr int IMG = 34 * 34 * 64;            // u16 per (slot,b,cg) image
constexpr size_t SLOTI = 16ull * IMG;        // u16 per h slot (8 b x 2 cg)
constexpr int ROWB = 34 * 128;               // bytes per image row (4352)
constexpr int PADB = 8192;                   // tail slack for DMA overshoot
}
template <int N> struct IC { static constexpr int v = N; };

__device__ __forceinline__ uint16_t bf16_rne(float x) {
  uint32_t u = __builtin_bit_cast(uint32_t, x);
  return (uint16_t)((u + 0x7FFFu + ((u >> 16) & 1u)) >> 16);
}
__device__ __forceinline__ float bf16_to_f(uint16_t h) {
  uint32_t u = ((uint32_t)h) << 16;
  return __builtin_bit_cast(float, u);
}

__device__ __forceinline__ void gl_lds16(const void* g, void* l) {
  __builtin_amdgcn_global_load_lds(
      (const __attribute__((address_space(1))) void*)g,
      (__attribute__((address_space(3))) void*)l, 16, 0, 0);
}

// ---- feature pack: fp32 [B][T][128][32][32] -> swizzled images [t][b][4cg] ----
__global__ void pack_features(const float* __restrict__ f, uint16_t* __restrict__ out) {
  const size_t i = (size_t)blockIdx.x * 256 + threadIdx.x;  // 16B-block index, < 2367488
  const int blk_s = (int)(i & 7);
  size_t pp = i >> 3;
  const int px = (int)(pp % 34); pp /= 34;
  const int yy = (int)(pp % 34); pp /= 34;
  const int cg = (int)(pp & 3);
  const int bt = (int)(pp >> 2);
  const int b = bt & 7, t = bt >> 3;
  const int blk = blk_s ^ (px & 7);
  const int pl = blk >> 2, kg = blk & 3;
  short8 sv;
  if (px == 0 || px == 33 || yy == 0 || yy == 33) {
    #pragma unroll
    for (int j = 0; j < 8; ++j) sv[j] = 0;
  } else {
    const int x = px - 1, y = yy - 1;
    #pragma unroll
    for (int j = 0; j < 8; ++j) {
      const int ch = cg * 32 + kg * 8 + j;
      const float fv = f[(((size_t)b * 8 + t) * 128 + ch) * 1024 + y * 32 + x];
      const uint16_t hi = bf16_rne(fv);
      sv[j] = (short)(pl ? bf16_rne(fv - bf16_to_f(hi)) : hi);
    }
  }
  *(short8*)(out + i * 8) = sv;
}

// ---- weight pack into swizzled images: per combo [cg][tap][nt][4096 u32] ----
struct WPackArgs {
  const float* wih[4]; const float* whh[4];
  const float* bih[4]; const float* bhh[4];
  uint32_t* wp; float* bp;
};
__global__ void pack_weights(WPackArgs A) {
  const int combo = blockIdx.y;
  const int idx = blockIdx.x * 256 + threadIdx.x;  // < 442368
  const int q = idx & 4095;
  const int rest = idx >> 12;
  const int nt = rest & 1;
  const int ct = rest >> 1;          // cg*9+tap
  const int tap = ct % 9, cg = ct / 9;
  const int w2 = q & 3;
  const int b8s = (q >> 2) & 7;
  const int hcp = (q >> 5) & 15;
  const int g = (q >> 9) & 3;
  const int pl = (q >> 11) & 1;
  const int b8 = b8s ^ (hcp & 7);
  const int kg = b8 & 3;
  const int hcl = hcp * 2 + (b8 >> 2);
  const int n = g * 64 + nt * 32 + hcl;
  const float* wih = A.wih[combo];
  const float* whh = A.whh[combo];
  uint32_t out = 0;
  #pragma unroll
  for (int e = 0; e < 2; ++e) {
    const int ch = cg * 32 + kg * 8 + w2 * 2 + e;
    const float wv = (ch < 128) ? wih[((size_t)n * 128 + ch) * 9 + tap]
                                : whh[((size_t)n * 64 + (ch - 128)) * 9 + tap];
    const uint16_t hi = bf16_rne(wv);
    const uint16_t v = pl ? bf16_rne(wv - bf16_to_f(hi)) : hi;
    out |= ((uint32_t)v) << (16 * e);
  }
  A.wp[(size_t)combo * 442368 + idx] = out;
  if (idx < 256) A.bp[combo * 256 + idx] = A.bih[combo][idx] + A.bhh[combo][idx];
}

struct StepArgs {
  const uint16_t* in0; const uint16_t* in1; const uint16_t* in2;  // images
  int nc0, nc1, nc2;         // cg counts per tensor
  const uint32_t* W;         // combo base: [cg][tap][nt][4096 u32]
  const float* bias;         // [256], n = gate*64+hc
  float* cbuf;               // plain fp32 [b][64][1024]
  uint16_t* himg;            // nullable: [b][2 cg][IMG]
  float* hf32;               // nullable: plain [b][64][1024]
};

// Block: b = bx>>4, 4-row band (bx>>1)&7, nt = bx&1. 512 threads = 8 waves;
// wave w: row r = w&3, hc-subgroup hcg = w>>2. Per wave: 2 x-halves x 4 gates.
__global__ __launch_bounds__(512, 2) void conv_lstm_step(StepArgs A0, StepArgs A1) {
  extern __shared__ char smem[];
  char* Asm_ = smem;               // 2 x 32768 (A double-buffer; 26112 used each)
  char* Wsm_ = smem + 65536;       // 4 x 16384 (W quad-buffer)

  const StepArgs a = (blockIdx.z == 0) ? A0 : A1;
  const int bx = blockIdx.x;
  const int nt = bx & 1;
  const int band = (bx >> 1) & 7;
  const int b = bx >> 4;
  const int y0 = band * 4;
  const int tid = threadIdx.x;
  const int lane = tid & 63;
  const int w = tid >> 6;
  const int m15 = lane & 15;
  const int kg = lane >> 4;
  const int r = w & 3;
  const int hcg = w >> 2;

  // fragment read offsets (bytes), conflict-free via baked swizzle
  int offA[2][3][2];
  #pragma unroll
  for (int xh = 0; xh < 2; ++xh)
    #pragma unroll
    for (int kx = 0; kx < 3; ++kx)
      #pragma unroll
      for (int pl = 0; pl < 2; ++pl) {
        const int px = xh * 16 + kx + m15;
        const int sw = (pl * 4 + kg) ^ (px & 7);
        offA[xh][kx][pl] = r * ROWB + px * 128 + sw * 16;
      }
  int offW[2][4];
  {
    const int hcp = hcg * 8 + (m15 >> 1);
    const int b8 = kg + 4 * (m15 & 1);
    #pragma unroll
    for (int pl = 0; pl < 2; ++pl)
      #pragma unroll
      for (int g = 0; g < 4; ++g)
        offW[pl][g] = (((pl * 4 + g) * 16 + hcp) * 8 + (b8 ^ (hcp & 7))) * 16;
  }

  const int ncg = a.nc0 + a.nc1 + a.nc2;
  auto abase = [&](int cg) -> const char* {
    const uint16_t* t;
    if (cg < a.nc0) t = a.in0 + ((size_t)b * a.nc0 + cg) * IMG;
    else if (cg < a.nc0 + a.nc1) t = a.in1 + ((size_t)b * a.nc1 + (cg - a.nc0)) * IMG;
    else t = a.in2 + ((size_t)b * a.nc2 + (cg - a.nc0 - a.nc1)) * IMG;
    return (const char*)t + (size_t)y0 * ROWB;
  };
  // 4 chunks/wave (32 KB; 26112 used, tail lands in dead LDS; source has PADB slack)
  auto stageA = [&](int cgi, int par) {
    const char* g = abase(cgi);
    char* d = Asm_ + par * 32768;
    #pragma unroll
    for (int j = 0; j < 4; ++j)
      gl_lds16(g + (size_t)(4 * w + j) * 1024 + lane * 16, d + (4 * w + j) * 1024);
  };
  // W: running wave-uniform source pointer, 2 chunks/wave per 16 KB tile
  const char* const wbeg = (const char*)a.W + (size_t)nt * 16384;
  const char* const wend = (const char*)a.W + (size_t)ncg * 9 * 32768;
  const char* wsrc = wbeg;
  auto stageW = [&](int slot) {
    char* d = Wsm_ + slot * 16384;
    #pragma unroll
    for (int j = 0; j < 2; ++j)
      gl_lds16(wsrc + (size_t)(2 * w + j) * 1024 + lane * 16, d + (2 * w + j) * 1024);
    wsrc += 32768;
    if (wsrc >= wend) wsrc = wbeg;   // dummy restage near the tail (valid memory)
  };

  short8 af[2][2][2];  // [set][xh][pl]
  short8 wf[2][2][4];  // [set][pl][g]
  float4v acc[2][4];
  #pragma unroll
  for (int xh = 0; xh < 2; ++xh)
    #pragma unroll
    for (int g = 0; g < 4; ++g) acc[xh][g] = (float4v){0.f, 0.f, 0.f, 0.f};

  // issue 12 ds_reads for tap TAP into register set S
  auto issue_reads = [&](auto sc, auto tc, const char* Apar, const char* Wb) {
    constexpr int S = decltype(sc)::v;
    constexpr int TAP = decltype(tc)::v;
    constexpr int ky = TAP / 3, kx = TAP % 3;
    const char* Ab = Apar + ky * ROWB;
    #pragma unroll
    for (int xh = 0; xh < 2; ++xh)
      #pragma unroll
      for (int pl = 0; pl < 2; ++pl)
        af[S][xh][pl] = *(const short8*)(Ab + offA[xh][kx][pl]);
    #pragma unroll
    for (int pl = 0; pl < 2; ++pl)
      #pragma unroll
      for (int g = 0; g < 4; ++g)
        wf[S][pl][g] = *(const short8*)(Wb + offW[pl][g]);
  };
  auto run_mfma = [&](auto sc) {
    constexpr int S = decltype(sc)::v;
    #pragma unroll
    for (int xh = 0; xh < 2; ++xh)
      #pragma unroll
      for (int g = 0; g < 4; ++g) {
        acc[xh][g] = __builtin_amdgcn_mfma_f32_16x16x32_bf16(af[S][xh][0], wf[S][0][g], acc[xh][g], 0, 0, 0);
        acc[xh][g] = __builtin_amdgcn_mfma_f32_16x16x32_bf16(af[S][xh][0], wf[S][1][g], acc[xh][g], 0, 0, 0);
        acc[xh][g] = __builtin_amdgcn_mfma_f32_16x16x32_bf16(af[S][xh][1], wf[S][0][g], acc[xh][g], 0, 0, 0);
      }
  };

  // Prologue: A[0], W0..W2; drain A0+W0; read tap0 fragments (left in flight).
  stageA(0, 0);
  stageW(0); stageW(1); stageW(2);
  asm volatile("s_waitcnt vmcnt(4)" ::: "memory");
  __builtin_amdgcn_s_barrier();
  issue_reads(IC<0>{}, IC<0>{}, Asm_, Wsm_);

  // cg-pair bodies: 18 taps each, compile-time slot/set/parity (cgbase even).
  auto pair = [&](auto pbc, int cgbase) {
    constexpr int PB = decltype(pbc)::v;   // (cgbase/2) & 1  ->  cgbase%4 == 2*PB
    auto body = [&](auto tc2) {
      constexpr int t = decltype(tc2)::v;  // 0..17; lin = 9*cgbase + t
      constexpr int TAP = t % 9;
      constexpr int CNT = (TAP == 1 || TAP == 2) ? 6 : 2;
      constexpr int S = t & 1;
      asm volatile("s_waitcnt vmcnt(%0)" :: "n"(CNT) : "memory");
      __builtin_amdgcn_s_barrier();
      stageW((2 * PB + t + 3) & 3);        // W[lin+3]
      if (TAP == 0) {                      // A[cg+1] into opposite parity
        const int cg = cgbase + t / 9;
        const int nx = (cg + 1 < ncg) ? cg + 1 : 0;
        stageA(nx, (cg + 1) & 1);
      }
      // early reads for tap t+1 (W[t+1] complete per vmcnt schedule above)
      issue_reads(IC<S ^ 1>{}, IC<(t + 1) % 9>{},
                  Asm_ + (((t + 1) / 9) & 1) * 32768,
                  Wsm_ + ((2 * PB + t + 1) & 3) * 16384);
      asm volatile("s_waitcnt lgkmcnt(12)" ::: "memory");  // drain set S, keep S^1
      __builtin_amdgcn_sched_barrier(0);                   // rule #18
      __builtin_amdgcn_s_setprio(1);
      run_mfma(IC<S>{});
      __builtin_amdgcn_s_setprio(0);
    };
    body(IC<0>{});  body(IC<1>{});  body(IC<2>{});  body(IC<3>{});  body(IC<4>{});
    body(IC<5>{});  body(IC<6>{});  body(IC<7>{});  body(IC<8>{});  body(IC<9>{});
    body(IC<10>{}); body(IC<11>{}); body(IC<12>{}); body(IC<13>{}); body(IC<14>{});
    body(IC<15>{}); body(IC<16>{}); body(IC<17>{});
  };
  pair(IC<0>{}, 0);
  pair(IC<1>{}, 2);
  if (ncg == 6) pair(IC<0>{}, 4);

  asm volatile("s_waitcnt vmcnt(0) lgkmcnt(0)" ::: "memory");  // drain dummies

  // ---- fused LSTM cell epilogue ----
  const int hcl = hcg * 16 + m15;
  const int hc = nt * 32 + hcl;
  const int y = y0 + r;
  float bi[4];
  #pragma unroll
  for (int g = 0; g < 4; ++g) bi[g] = a.bias[g * 64 + hc];
  float* crow = a.cbuf + ((size_t)(b * 64 + hc)) * 1024 + y * 32;
  float* hrow = a.hf32 ? a.hf32 + ((size_t)(b * 64 + hc)) * 1024 + y * 32 : nullptr;
  uint16_t* hb = a.himg ? a.himg + ((size_t)(b * 2 + nt)) * IMG : nullptr;
  const int kgb = hcl >> 3, jj = hcl & 7;
  #pragma unroll
  for (int xh = 0; xh < 2; ++xh) {
    const int x0 = xh * 16 + kg * 4;
    float4v cv = *(float4v*)(crow + x0);
    float4v cn, hn;
    #pragma unroll
    for (int q = 0; q < 4; ++q) {
      const float ig = 1.f / (1.f + expf(-(acc[xh][0][q] + bi[0])));
      const float fg = 1.f / (1.f + expf(-(acc[xh][1][q] + bi[1])));
      const float gg = tanhf(acc[xh][2][q] + bi[2]);
      const float og = 1.f / (1.f + expf(-(acc[xh][3][q] + bi[3])));
      const float c2 = fg * cv[q] + ig * gg;
      cn[q] = c2;
      hn[q] = og * tanhf(c2);
    }
    *(float4v*)(crow + x0) = cn;
    if (hrow) *(float4v*)(hrow + x0) = hn;
    if (hb) {
      #pragma unroll
      for (int q = 0; q < 4; ++q) {
        const int px = x0 + q + 1;
        const int sw = px & 7;
        const uint16_t hi = bf16_rne(hn[q]);
        const uint16_t lo = bf16_rne(hn[q] - bf16_to_f(hi));
        const size_t p16 = ((size_t)(y + 1) * 34 + px) * 64;
        hb[p16 + (size_t)(kgb ^ sw) * 8 + jj] = hi;
        hb[p16 + (size_t)((4 + kgb) ^ sw) * 8 + jj] = lo;
      }
    }
  }
  if (hb) {   // keep image borders zero (ws is re-poisoned every call)
    {
      const int rr = tid >> 7;             // 0..3
      const int hlf = (tid >> 6) & 1;
      const int jx = tid & 63;
      hb[((size_t)(y0 + 1 + rr) * 34 + hlf * 33) * 64 + jx] = 0;
    }
    if (band == 0) for (int i = tid; i < 2176; i += 512) hb[i] = 0;
    if (band == 7) for (int i = tid; i < 2176; i += 512) hb[(size_t)33 * 2176 + i] = 0;
  }
}

// out[b][o][p] = relu(b_out[o] + sum_c w_out[o][c] * last[b][c][p])  (fp32 inputs)
__global__ void final_conv(const float* __restrict__ h1f_last, const float* __restrict__ h1r_last,
                           const float* __restrict__ wout, const float* __restrict__ bout,
                           float* __restrict__ out) {
  __shared__ float Ws[16 * 128];
  const int oq = blockIdx.y;
  for (int i = threadIdx.x; i < 16 * 128; i += 256) Ws[i] = wout[oq * 16 * 128 + i];
  __syncthreads();
  const int gp = blockIdx.x * 256 + threadIdx.x;
  const int b = gp >> 10, p = gp & 1023;
  float acc[16];
  #pragma unroll
  for (int o = 0; o < 16; ++o) acc[o] = bout[oq * 16 + o];
  for (int c = 0; c < 128; ++c) {
    const float xv = (c < 64) ? h1f_last[((size_t)b * 64 + c) * 1024 + p]
                              : h1r_last[((size_t)b * 64 + (c - 64)) * 1024 + p];
    #pragma unroll
    for (int o = 0; o < 16; ++o) acc[o] = fmaf(xv, Ws[o * 128 + c], acc[o]);
  }
  #pragma unroll
  for (int o = 0; o < 16; ++o) {
    const float v = acc[o];
    out[((size_t)b * 64 + oq * 16 + o) * 1024 + p] = v > 0.f ? v : 0.f;
  }
}

extern "C" void kernel_launch(void* const* d_in, const int* in_sizes, int n_in,
                              void* d_out, int out_size, void* d_ws, size_t ws_size,
                              hipStream_t stream) {
  char* p = (char*)d_ws;
  uint16_t* featImg = (uint16_t*)p; p += (size_t)8 * 8 * 4 * IMG * 2 + PADB;  // 37.9 MB
  uint32_t* WP = (uint32_t*)p;      p += (size_t)4 * 442368 * 4;              // 7.1 MB
  float* bp = (float*)p;            p += 4096;
  uint16_t* hf0i = (uint16_t*)p;    p += (size_t)9 * SLOTI * 2 + PADB;        // 21.3 MB
  uint16_t* hr0i = (uint16_t*)p;    p += (size_t)9 * SLOTI * 2 + PADB;        // 21.3 MB
  uint16_t* h1fi = (uint16_t*)p;    p += (size_t)2 * SLOTI * 2 + PADB;        // 4.7 MB
  float* c0f = (float*)p;           p += (size_t)4 * 2097152;                 // c states
  float* c0r = c0f + 524288;
  float* c1f = c0r + 524288;
  float* c1r = c1f + 524288;
  float* h1f8 = (float*)p;          p += 2097152;
  float* h1r8 = (float*)p;          p += 2097152;

  hipMemsetAsync(c0f, 0, (size_t)4 * 2097152, stream);
  hipMemsetAsync(hf0i, 0, (size_t)SLOTI * 2, stream);                     // hf0 slot 0
  hipMemsetAsync(hr0i + (size_t)8 * SLOTI, 0, (size_t)SLOTI * 2, stream); // hr0 slot 8
  hipMemsetAsync(h1fi, 0, (size_t)SLOTI * 2, stream);                     // h1f parity-0 slot

  pack_features<<<dim3(9248), 256, 0, stream>>>((const float*)d_in[0], featImg);

  WPackArgs wa;
  for (int combo = 0; combo < 4; ++combo) {
    const int base = 1 + combo * 4;
    wa.wih[combo] = (const float*)d_in[base];
    wa.whh[combo] = (const float*)d_in[base + 1];
    wa.bih[combo] = (const float*)d_in[base + 2];
    wa.bhh[combo] = (const float*)d_in[base + 3];
  }
  wa.wp = WP; wa.bp = bp;
  pack_weights<<<dim3(1728, 4), 256, 0, stream>>>(wa);

  constexpr int DYN_LDS = 131072;   // 2x32KB A + 4x16KB W
  (void)hipFuncSetAttribute((const void*)conv_lstm_step,
                            hipFuncAttributeMaxDynamicSharedMemorySize, DYN_LDS);

  auto mk = [&](const uint16_t* i0, int n0, const uint16_t* i1, int n1,
                const uint16_t* i2, int n2, int combo, float* cb,
                uint16_t* himg, float* hf32) {
    StepArgs s;
    s.in0 = i0; s.in1 = i1; s.in2 = i2;
    s.nc0 = n0; s.nc1 = n1; s.nc2 = n2;
    s.W = WP + (size_t)combo * 442368; s.bias = bp + combo * 256;
    s.cbuf = cb; s.himg = himg; s.hf32 = hf32;
    return s;
  };

  // Layer 0: 8 pair launches (fwd step k, rev step 7-k); 128 blocks/dir, 512 thr.
  for (int k = 0; k < 8; ++k) {
    const int tr = 7 - k;
    StepArgs f = mk(featImg + (size_t)k * 8 * 4 * IMG, 4,
                    hf0i + (size_t)k * SLOTI, 2, nullptr, 0,
                    0, c0f, hf0i + (size_t)(k + 1) * SLOTI, nullptr);
    StepArgs r = mk(featImg + (size_t)tr * 8 * 4 * IMG, 4,
                    hr0i + (size_t)(tr + 1) * SLOTI, 2, nullptr, 0,
                    1, c0r, hr0i + (size_t)tr * SLOTI, nullptr);
    conv_lstm_step<<<dim3(128, 1, 2), 512, DYN_LDS, stream>>>(f, r);
  }

  // Layer 1: fwd t=0 pairs with the single reverse step (t=7, zero init state).
  for (int t = 0; t < 8; ++t) {
    uint16_t* himg = (t < 7) ? h1fi + (size_t)((t + 1) & 1) * SLOTI : nullptr;
    float* hf32 = (t == 7) ? h1f8 : nullptr;
    StepArgs s = mk(hf0i + (size_t)(t + 1) * SLOTI, 2, hr0i + (size_t)t * SLOTI, 2,
                    h1fi + (size_t)(t & 1) * SLOTI, 2, 2, c1f, himg, hf32);
    if (t == 0) {
      StepArgs rv = mk(hf0i + (size_t)8 * SLOTI, 2, hr0i + (size_t)7 * SLOTI, 2,
                       nullptr, 0, 3, c1r, nullptr, h1r8);
      conv_lstm_step<<<dim3(128, 1, 2), 512, DYN_LDS, stream>>>(s, rv);
    } else {
      conv_lstm_step<<<dim3(128, 1, 1), 512, DYN_LDS, stream>>>(s, s);
    }
  }

  final_conv<<<dim3(32, 4), 256, 0, stream>>>(
      h1f8, h1r8, (const float*)d_in[17], (const float*)d_in[18], (float*)d_out);
}

// Round 3
// 725.540 us; speedup vs baseline: 1.0925x; 1.0925x over previous
//
#include <hip/hip_runtime.h>
#include <math.h>
#include <stdint.h>

// ConvLSTM (Seq2VecRNN2D) round 8: revert to round-0 inner loop (proven 42.5us:
// tap-granularity, W triple-buffer, counted vmcnt, synchronous fragment reads).
// NEW: kernel templated on ROWS (band height). Paired launches use ROWS=4
// (512 thr, 128 blocks x z=2, identical to round 0). The 7 solo layer-1 launches
// use ROWS=2: 256 blocks x 256 thr (4 waves) so ALL CUs are busy (was 128 blocks
// = half GPU idle). Wave tile stays 32x64; per-CU LDS read traffic halves.
// B=8 T=8 CIN=128 HID=64 G=256 H=W=32.
//
// Activation image per (slot,b,cg32): [34 y'][34 px][8 blk of 16B], blk = pl*4+kg
// stored at blk^(px&7); ch = cg*32+kg*8+j, pl0=hi bf16, pl1=lo bf16. Borders zero.
// Weight image per (combo,cg,tap,nt): [pl][4 g][16 hcp][8 b8 of 16B], b8 = kg+4*(hc&1)
// stored at b8^(hcp&7); hcp = hc_local>>1.
//
// DMA schedule (per wave, per barrier interval): WCH W chunks always; +ACH A chunks
// at tap==0. vmcnt before barrier of tap t (in-order retirement, queue-simulated):
//   ROWS=4 (ACH=4,WCH=2): tap0: 2, tap1: 6, tap2: 6, tap>=3: 2   (round-0 exact)
//   ROWS=2 (ACH=5,WCH=4): tap0: 4, tap1: 9, tap2: 9, tap>=3: 4

typedef __attribute__((ext_vector_type(8))) short short8;
typedef __attribute__((ext_vector_type(4))) float float4v;

namespace {
constexpr int IMG = 34 * 34 * 64;            // u16 per (slot,b,cg) image
constexpr size_t SLOTI = 16ull * IMG;        // u16 per h slot (8 b x 2 cg)
constexpr int ROWB = 34 * 128;               // bytes per image row (4352)
constexpr int PADB = 8192;                   // tail slack for DMA overshoot
}
template <int N> struct IC { static constexpr int v = N; };

__device__ __forceinline__ uint16_t bf16_rne(float x) {
  uint32_t u = __builtin_bit_cast(uint32_t, x);
  return (uint16_t)((u + 0x7FFFu + ((u >> 16) & 1u)) >> 16);
}
__device__ __forceinline__ float bf16_to_f(uint16_t h) {
  uint32_t u = ((uint32_t)h) << 16;
  return __builtin_bit_cast(float, u);
}

__device__ __forceinline__ void gl_lds16(const void* g, void* l) {
  __builtin_amdgcn_global_load_lds(
      (const __attribute__((address_space(1))) void*)g,
      (__attribute__((address_space(3))) void*)l, 16, 0, 0);
}

// ---- feature pack: fp32 [B][T][128][32][32] -> swizzled images [t][b][4cg] ----
__global__ void pack_features(const float* __restrict__ f, uint16_t* __restrict__ out) {
  const size_t i = (size_t)blockIdx.x * 256 + threadIdx.x;  // 16B-block index, < 2367488
  const int blk_s = (int)(i & 7);
  size_t pp = i >> 3;
  const int px = (int)(pp % 34); pp /= 34;
  const int yy = (int)(pp % 34); pp /= 34;
  const int cg = (int)(pp & 3);
  const int bt = (int)(pp >> 2);
  const int b = bt & 7, t = bt >> 3;
  const int blk = blk_s ^ (px & 7);
  const int pl = blk >> 2, kg = blk & 3;
  short8 sv;
  if (px == 0 || px == 33 || yy == 0 || yy == 33) {
    #pragma unroll
    for (int j = 0; j < 8; ++j) sv[j] = 0;
  } else {
    const int x = px - 1, y = yy - 1;
    #pragma unroll
    for (int j = 0; j < 8; ++j) {
      const int ch = cg * 32 + kg * 8 + j;
      const float fv = f[(((size_t)b * 8 + t) * 128 + ch) * 1024 + y * 32 + x];
      const uint16_t hi = bf16_rne(fv);
      sv[j] = (short)(pl ? bf16_rne(fv - bf16_to_f(hi)) : hi);
    }
  }
  *(short8*)(out + i * 8) = sv;
}

// ---- weight pack into swizzled images: per combo [cg][tap][nt][4096 u32] ----
struct WPackArgs {
  const float* wih[4]; const float* whh[4];
  const float* bih[4]; const float* bhh[4];
  uint32_t* wp; float* bp;
};
__global__ void pack_weights(WPackArgs A) {
  const int combo = blockIdx.y;
  const int idx = blockIdx.x * 256 + threadIdx.x;  // < 442368
  const int q = idx & 4095;
  const int rest = idx >> 12;
  const int nt = rest & 1;
  const int ct = rest >> 1;          // cg*9+tap
  const int tap = ct % 9, cg = ct / 9;
  const int w2 = q & 3;
  const int b8s = (q >> 2) & 7;
  const int hcp = (q >> 5) & 15;
  const int g = (q >> 9) & 3;
  const int pl = (q >> 11) & 1;
  const int b8 = b8s ^ (hcp & 7);
  const int kg = b8 & 3;
  const int hcl = hcp * 2 + (b8 >> 2);
  const int n = g * 64 + nt * 32 + hcl;
  const float* wih = A.wih[combo];
  const float* whh = A.whh[combo];
  uint32_t out = 0;
  #pragma unroll
  for (int e = 0; e < 2; ++e) {
    const int ch = cg * 32 + kg * 8 + w2 * 2 + e;
    const float wv = (ch < 128) ? wih[((size_t)n * 128 + ch) * 9 + tap]
                                : whh[((size_t)n * 64 + (ch - 128)) * 9 + tap];
    const uint16_t hi = bf16_rne(wv);
    const uint16_t v = pl ? bf16_rne(wv - bf16_to_f(hi)) : hi;
    out |= ((uint32_t)v) << (16 * e);
  }
  A.wp[(size_t)combo * 442368 + idx] = out;
  if (idx < 256) A.bp[combo * 256 + idx] = A.bih[combo][idx] + A.bhh[combo][idx];
}

struct StepArgs {
  const uint16_t* in0; const uint16_t* in1; const uint16_t* in2;  // images
  int nc0, nc1, nc2;         // cg counts per tensor
  const uint32_t* W;         // combo base: [cg][tap][nt][4096 u32]
  const float* bias;         // [256], n = gate*64+hc
  float* cbuf;               // plain fp32 [b][64][1024]
  uint16_t* himg;            // nullable: [b][2 cg][IMG]
  float* hf32;               // nullable: plain [b][64][1024]
};

// ROWS=4: 512 thr, grid bx = b(8) x band(8) x nt(2);  wave: r=w&3, hcg=w>>2.
// ROWS=2: 256 thr, grid bx = b(8) x band(16) x nt(2); wave: r=w&1, hcg=w>>1.
// Per wave: 2 x-halves x 4 gates (tile 32x64).
template <int ROWS>
__global__ __launch_bounds__(ROWS * 128, ROWS / 2) void conv_lstm_step(StepArgs A0, StepArgs A1) {
  constexpr int NW = ROWS * 2;                 // waves per block
  constexpr int THREADS = NW * 64;
  constexpr int BANDS = 32 / ROWS;
  constexpr int LOGB = (ROWS == 4) ? 3 : 4;
  constexpr int ACH = (ROWS == 4) ? 4 : 5;     // A chunks per wave
  constexpr int ASLOT = ACH * NW * 1024;       // 32768 / 20480
  constexpr int WCH = 16384 / (NW * 1024);     // W chunks per wave: 2 / 4
  constexpr int CNT0 = WCH;                    // taps 0, >=3
  constexpr int CNT12 = WCH + ACH;             // taps 1,2:  6 / 9

  extern __shared__ char smem[];
  char* Asm_ = smem;                           // 2 x ASLOT (A double-buffer)
  char* Wsm_ = smem + 2 * ASLOT;               // 3 x 16384 (W triple-buffer)

  const StepArgs a = (blockIdx.z == 0) ? A0 : A1;
  const int bx = blockIdx.x;
  const int nt = bx & 1;
  const int band = (bx >> 1) & (BANDS - 1);
  const int b = bx >> (1 + LOGB);
  const int y0 = band * ROWS;
  const int tid = threadIdx.x;
  const int lane = tid & 63;
  const int w = tid >> 6;
  const int m15 = lane & 15;
  const int kg = lane >> 4;
  const int r = w & (ROWS - 1);
  const int hcg = (ROWS == 4) ? (w >> 2) : (w >> 1);

  // fragment read offsets (bytes), conflict-free via baked swizzle
  int offA[2][3][2];
  #pragma unroll
  for (int xh = 0; xh < 2; ++xh)
    #pragma unroll
    for (int kx = 0; kx < 3; ++kx)
      #pragma unroll
      for (int pl = 0; pl < 2; ++pl) {
        const int px = xh * 16 + kx + m15;
        const int sw = (pl * 4 + kg) ^ (px & 7);
        offA[xh][kx][pl] = r * ROWB + px * 128 + sw * 16;
      }
  int offW[2][4];
  {
    const int hcp = hcg * 8 + (m15 >> 1);
    const int b8 = kg + 4 * (m15 & 1);
    #pragma unroll
    for (int pl = 0; pl < 2; ++pl)
      #pragma unroll
      for (int g = 0; g < 4; ++g)
        offW[pl][g] = (((pl * 4 + g) * 16 + hcp) * 8 + (b8 ^ (hcp & 7))) * 16;
  }

  const int ncg = a.nc0 + a.nc1 + a.nc2;
  auto abase = [&](int cg) -> const char* {
    const uint16_t* t;
    if (cg < a.nc0) t = a.in0 + ((size_t)b * a.nc0 + cg) * IMG;
    else if (cg < a.nc0 + a.nc1) t = a.in1 + ((size_t)b * a.nc1 + (cg - a.nc0)) * IMG;
    else t = a.in2 + ((size_t)b * a.nc2 + (cg - a.nc0 - a.nc1)) * IMG;
    return (const char*)t + (size_t)y0 * ROWB;
  };
  // ACH chunks/wave (ROWS+2 rows used, tail lands in dead LDS; source has PADB slack)
  auto stageA = [&](int cgi, int par) {
    const char* g = abase(cgi);
    char* d = Asm_ + par * ASLOT;
    #pragma unroll
    for (int j = 0; j < ACH; ++j)
      gl_lds16(g + (size_t)(ACH * w + j) * 1024 + lane * 16, d + (ACH * w + j) * 1024);
  };
  // WCH chunks/wave (16 KB tile)
  auto stageW = [&](int cgs, int taps, int slot) {
    const char* g = (const char*)a.W + ((size_t)((cgs * 9 + taps) * 2 + nt) << 14);
    char* d = Wsm_ + slot * 16384;
    #pragma unroll
    for (int j = 0; j < WCH; ++j)
      gl_lds16(g + (size_t)(WCH * w + j) * 1024 + lane * 16, d + (WCH * w + j) * 1024);
  };

  float4v acc[2][4];
  #pragma unroll
  for (int xh = 0; xh < 2; ++xh)
    #pragma unroll
    for (int g = 0; g < 4; ++g) acc[xh][g] = (float4v){0.f, 0.f, 0.f, 0.f};

  // Prologue: A[0] then W[0,0], W[0,1] (order matters for vmcnt math).
  stageA(0, 0);
  stageW(0, 0, 0);
  stageW(0, 1, 1);

  for (int cg = 0; cg < ncg; ++cg) {
    auto tap_body = [&](auto tapc) {
      constexpr int TAP = decltype(tapc)::v;
      constexpr int CNT = (TAP == 1 || TAP == 2) ? CNT12 : CNT0;
      asm volatile("s_waitcnt vmcnt(%0)\n\ts_barrier" :: "n"(CNT) : "memory");
      const int lin = cg * 9 + TAP;
      {  // stage W for lin+2 (wrap to a dead-but-valid tile near the end)
        const int l2 = lin + 2;
        int cgs = l2 / 9;
        const int taps = l2 % 9;
        if (cgs >= ncg) cgs = 0;
        stageW(cgs, taps, l2 % 3);
      }
      if (TAP == 0) {  // stage next cg's A into the other parity
        const int nx = (cg + 1 < ncg) ? cg + 1 : 0;
        stageA(nx, (cg + 1) & 1);
      }
      constexpr int ky = TAP / 3, kx = TAP % 3;
      const char* Ab = Asm_ + (cg & 1) * ASLOT + ky * ROWB;
      const char* Wb = Wsm_ + (lin % 3) * 16384;
      short8 af[2][2];
      #pragma unroll
      for (int xh = 0; xh < 2; ++xh)
        #pragma unroll
        for (int pl = 0; pl < 2; ++pl)
          af[xh][pl] = *(const short8*)(Ab + offA[xh][kx][pl]);
      short8 wfr[2][4];
      #pragma unroll
      for (int pl = 0; pl < 2; ++pl)
        #pragma unroll
        for (int g = 0; g < 4; ++g)
          wfr[pl][g] = *(const short8*)(Wb + offW[pl][g]);
      #pragma unroll
      for (int xh = 0; xh < 2; ++xh)
        #pragma unroll
        for (int g = 0; g < 4; ++g) {
          acc[xh][g] = __builtin_amdgcn_mfma_f32_16x16x32_bf16(af[xh][0], wfr[0][g], acc[xh][g], 0, 0, 0);
          acc[xh][g] = __builtin_amdgcn_mfma_f32_16x16x32_bf16(af[xh][0], wfr[1][g], acc[xh][g], 0, 0, 0);
          acc[xh][g] = __builtin_amdgcn_mfma_f32_16x16x32_bf16(af[xh][1], wfr[0][g], acc[xh][g], 0, 0, 0);
        }
    };
    tap_body(IC<0>{}); tap_body(IC<1>{}); tap_body(IC<2>{});
    tap_body(IC<3>{}); tap_body(IC<4>{}); tap_body(IC<5>{});
    tap_body(IC<6>{}); tap_body(IC<7>{}); tap_body(IC<8>{});
  }
  asm volatile("s_waitcnt vmcnt(0)" ::: "memory");  // drain dummy restages

  // ---- fused LSTM cell epilogue ----
  const int hcl = hcg * 16 + m15;
  const int hc = nt * 32 + hcl;
  const int y = y0 + r;
  float bi[4];
  #pragma unroll
  for (int g = 0; g < 4; ++g) bi[g] = a.bias[g * 64 + hc];
  float* crow = a.cbuf + ((size_t)(b * 64 + hc)) * 1024 + y * 32;
  float* hrow = a.hf32 ? a.hf32 + ((size_t)(b * 64 + hc)) * 1024 + y * 32 : nullptr;
  uint16_t* hb = a.himg ? a.himg + ((size_t)(b * 2 + nt)) * IMG : nullptr;
  const int kgb = hcl >> 3, jj = hcl & 7;
  #pragma unroll
  for (int xh = 0; xh < 2; ++xh) {
    const int x0 = xh * 16 + kg * 4;
    float4v cv = *(float4v*)(crow + x0);
    float4v cn, hn;
    #pragma unroll
    for (int q = 0; q < 4; ++q) {
      const float ig = 1.f / (1.f + expf(-(acc[xh][0][q] + bi[0])));
      const float fg = 1.f / (1.f + expf(-(acc[xh][1][q] + bi[1])));
      const float gg = tanhf(acc[xh][2][q] + bi[2]);
      const float og = 1.f / (1.f + expf(-(acc[xh][3][q] + bi[3])));
      const float c2 = fg * cv[q] + ig * gg;
      cn[q] = c2;
      hn[q] = og * tanhf(c2);
    }
    *(float4v*)(crow + x0) = cn;
    if (hrow) *(float4v*)(hrow + x0) = hn;
    if (hb) {
      #pragma unroll
      for (int q = 0; q < 4; ++q) {
        const int px = x0 + q + 1;
        const int sw = px & 7;
        const uint16_t hi = bf16_rne(hn[q]);
        const uint16_t lo = bf16_rne(hn[q] - bf16_to_f(hi));
        const size_t p16 = ((size_t)(y + 1) * 34 + px) * 64;
        hb[p16 + (size_t)(kgb ^ sw) * 8 + jj] = hi;
        hb[p16 + (size_t)((4 + kgb) ^ sw) * 8 + jj] = lo;
      }
    }
  }
  if (hb) {   // keep image borders zero (ws is re-poisoned every call)
    {
      const int rr = tid >> 7;             // 0..ROWS-1 (THREADS = ROWS*128)
      const int hlf = (tid >> 6) & 1;
      const int jx = tid & 63;
      hb[((size_t)(y0 + 1 + rr) * 34 + hlf * 33) * 64 + jx] = 0;
    }
    if (band == 0) for (int i = tid; i < 2176; i += THREADS) hb[i] = 0;
    if (band == BANDS - 1) for (int i = tid; i < 2176; i += THREADS) hb[(size_t)33 * 2176 + i] = 0;
  }
}

// out[b][o][p] = relu(b_out[o] + sum_c w_out[o][c] * last[b][c][p])  (fp32 inputs)
__global__ void final_conv(const float* __restrict__ h1f_last, const float* __restrict__ h1r_last,
                           const float* __restrict__ wout, const float* __restrict__ bout,
                           float* __restrict__ out) {
  __shared__ float Ws[16 * 128];
  const int oq = blockIdx.y;
  for (int i = threadIdx.x; i < 16 * 128; i += 256) Ws[i] = wout[oq * 16 * 128 + i];
  __syncthreads();
  const int gp = blockIdx.x * 256 + threadIdx.x;
  const int b = gp >> 10, p = gp & 1023;
  float acc[16];
  #pragma unroll
  for (int o = 0; o < 16; ++o) acc[o] = bout[oq * 16 + o];
  for (int c = 0; c < 128; ++c) {
    const float xv = (c < 64) ? h1f_last[((size_t)b * 64 + c) * 1024 + p]
                              : h1r_last[((size_t)b * 64 + (c - 64)) * 1024 + p];
    #pragma unroll
    for (int o = 0; o < 16; ++o) acc[o] = fmaf(xv, Ws[o * 128 + c], acc[o]);
  }
  #pragma unroll
  for (int o = 0; o < 16; ++o) {
    const float v = acc[o];
    out[((size_t)b * 64 + oq * 16 + o) * 1024 + p] = v > 0.f ? v : 0.f;
  }
}

extern "C" void kernel_launch(void* const* d_in, const int* in_sizes, int n_in,
                              void* d_out, int out_size, void* d_ws, size_t ws_size,
                              hipStream_t stream) {
  char* p = (char*)d_ws;
  uint16_t* featImg = (uint16_t*)p; p += (size_t)8 * 8 * 4 * IMG * 2 + PADB;  // 37.9 MB
  uint32_t* WP = (uint32_t*)p;      p += (size_t)4 * 442368 * 4;              // 7.1 MB
  float* bp = (float*)p;            p += 4096;
  uint16_t* hf0i = (uint16_t*)p;    p += (size_t)9 * SLOTI * 2 + PADB;        // 21.3 MB
  uint16_t* hr0i = (uint16_t*)p;    p += (size_t)9 * SLOTI * 2 + PADB;        // 21.3 MB
  uint16_t* h1fi = (uint16_t*)p;    p += (size_t)2 * SLOTI * 2 + PADB;        // 4.7 MB
  float* c0f = (float*)p;           p += (size_t)4 * 2097152;                 // c states
  float* c0r = c0f + 524288;
  float* c1f = c0r + 524288;
  float* c1r = c1f + 524288;
  float* h1f8 = (float*)p;          p += 2097152;
  float* h1r8 = (float*)p;          p += 2097152;

  hipMemsetAsync(c0f, 0, (size_t)4 * 2097152, stream);
  hipMemsetAsync(hf0i, 0, (size_t)SLOTI * 2, stream);                     // hf0 slot 0
  hipMemsetAsync(hr0i + (size_t)8 * SLOTI, 0, (size_t)SLOTI * 2, stream); // hr0 slot 8
  hipMemsetAsync(h1fi, 0, (size_t)SLOTI * 2, stream);                     // h1f parity-0 slot

  pack_features<<<dim3(9248), 256, 0, stream>>>((const float*)d_in[0], featImg);

  WPackArgs wa;
  for (int combo = 0; combo < 4; ++combo) {
    const int base = 1 + combo * 4;
    wa.wih[combo] = (const float*)d_in[base];
    wa.whh[combo] = (const float*)d_in[base + 1];
    wa.bih[combo] = (const float*)d_in[base + 2];
    wa.bhh[combo] = (const float*)d_in[base + 3];
  }
  wa.wp = WP; wa.bp = bp;
  pack_weights<<<dim3(1728, 4), 256, 0, stream>>>(wa);

  constexpr int DYN4 = 2 * 32768 + 3 * 16384;   // 114688: ROWS=4
  constexpr int DYN2 = 2 * 20480 + 3 * 16384;   // 90112:  ROWS=2
  (void)hipFuncSetAttribute((const void*)(conv_lstm_step<4>),
                            hipFuncAttributeMaxDynamicSharedMemorySize, DYN4);
  (void)hipFuncSetAttribute((const void*)(conv_lstm_step<2>),
                            hipFuncAttributeMaxDynamicSharedMemorySize, DYN2);

  auto mk = [&](const uint16_t* i0, int n0, const uint16_t* i1, int n1,
                const uint16_t* i2, int n2, int combo, float* cb,
                uint16_t* himg, float* hf32) {
    StepArgs s;
    s.in0 = i0; s.in1 = i1; s.in2 = i2;
    s.nc0 = n0; s.nc1 = n1; s.nc2 = n2;
    s.W = WP + (size_t)combo * 442368; s.bias = bp + combo * 256;
    s.cbuf = cb; s.himg = himg; s.hf32 = hf32;
    return s;
  };

  // Layer 0: 8 pair launches (fwd step k, rev step 7-k); 128 blocks/dir, 512 thr.
  for (int k = 0; k < 8; ++k) {
    const int tr = 7 - k;
    StepArgs f = mk(featImg + (size_t)k * 8 * 4 * IMG, 4,
                    hf0i + (size_t)k * SLOTI, 2, nullptr, 0,
                    0, c0f, hf0i + (size_t)(k + 1) * SLOTI, nullptr);
    StepArgs r = mk(featImg + (size_t)tr * 8 * 4 * IMG, 4,
                    hr0i + (size_t)(tr + 1) * SLOTI, 2, nullptr, 0,
                    1, c0r, hr0i + (size_t)tr * SLOTI, nullptr);
    conv_lstm_step<4><<<dim3(128, 1, 2), 512, DYN4, stream>>>(f, r);
  }

  // Layer 1: fwd t=0 pairs with the single reverse step (t=7, zero init state).
  // Solo steps t=1..7 use the ROWS=2 kernel: 256 blocks (full GPU), 256 thr.
  for (int t = 0; t < 8; ++t) {
    uint16_t* himg = (t < 7) ? h1fi + (size_t)((t + 1) & 1) * SLOTI : nullptr;
    float* hf32 = (t == 7) ? h1f8 : nullptr;
    StepArgs s = mk(hf0i + (size_t)(t + 1) * SLOTI, 2, hr0i + (size_t)t * SLOTI, 2,
                    h1fi + (size_t)(t & 1) * SLOTI, 2, 2, c1f, himg, hf32);
    if (t == 0) {
      StepArgs rv = mk(hf0i + (size_t)8 * SLOTI, 2, hr0i + (size_t)7 * SLOTI, 2,
                       nullptr, 0, 3, c1r, nullptr, h1r8);
      conv_lstm_step<4><<<dim3(128, 1, 2), 512, DYN4, stream>>>(s, rv);
    } else {
      conv_lstm_step<2><<<dim3(256, 1, 1), 256, DYN2, stream>>>(s, s);
    }
  }

  final_conv<<<dim3(32, 4), 256, 0, stream>>>(
      h1f8, h1r8, (const float*)d_in[17], (const float*)d_in[18], (float*)d_out);
}